// Round 2
// baseline (219.910 us; speedup 1.0000x reference)
//
#include <hip/hip_runtime.h>

#define D  512
#define HW 196   // 14*14

// ---------------------------------------------------------------------------
// Stage 1 (one launch): blocks 0..15 -> p, blocks 16..47 -> t12. No atomics.
//   p[b,j]   = m_prev[b,:] @ W_m[:,j] + b_m[j]
//   t12[b,kk]= sum_j u[b,j]*W_merge[kk][j],  u = c .* W_attn,  kk in [0,1024)
// ---------------------------------------------------------------------------
__global__ void k_stage1(const float* __restrict__ m_prev, const float* __restrict__ W_m,
                         const float* __restrict__ b_m, const float* __restrict__ c,
                         const float* __restrict__ W_attn, const float* __restrict__ W_merge,
                         float* __restrict__ p, float* __restrict__ t12) {
    const int bx = blockIdx.x;
    const int t  = threadIdx.x;
    __shared__ float xs[16][64];

    if (bx < 16) {                        // ---- p ----
        const int j  = (bx & 1) * 256 + t;      // 0..511
        const int b0 = (bx >> 1) * 16;
        float acc[16];
        #pragma unroll
        for (int bb = 0; bb < 16; ++bb) acc[bb] = 0.f;
        for (int k0 = 0; k0 < D; k0 += 64) {
            for (int i = t; i < 16 * 64; i += 256)
                xs[i >> 6][i & 63] = m_prev[(b0 + (i >> 6)) * D + k0 + (i & 63)];
            __syncthreads();
            for (int kk = 0; kk < 64; ++kk) {
                float wv = W_m[(k0 + kk) * D + j];   // coalesced across lanes
                #pragma unroll
                for (int bb = 0; bb < 16; ++bb) acc[bb] += xs[bb][kk] * wv;
            }
            __syncthreads();
        }
        const float bias = b_m[j];
        #pragma unroll
        for (int bb = 0; bb < 16; ++bb) p[(b0 + bb) * D + j] = acc[bb] + bias;
    } else {                              // ---- t12 ----
        const int i2 = bx - 16;
        const int kk = (i2 & 3) * 256 + t;      // 0..1023
        const int b0 = (i2 >> 2) * 16;
        float acc[16];
        #pragma unroll
        for (int bb = 0; bb < 16; ++bb) acc[bb] = 0.f;
        for (int j0 = 0; j0 < D; j0 += 64) {
            for (int i = t; i < 16 * 64; i += 256) {
                int bb = i >> 6, jj = i & 63;
                xs[bb][jj] = c[(b0 + bb) * D + j0 + jj] * W_attn[j0 + jj];
            }
            __syncthreads();
            const float4* wrow = (const float4*)&W_merge[kk * D + j0];
            for (int q = 0; q < 16; ++q) {
                float4 w4 = wrow[q];
                #pragma unroll
                for (int bb = 0; bb < 16; ++bb)
                    acc[bb] += xs[bb][4*q+0] * w4.x + xs[bb][4*q+1] * w4.y
                             + xs[bb][4*q+2] * w4.z + xs[bb][4*q+3] * w4.w;
            }
            __syncthreads();
        }
        #pragma unroll
        for (int bb = 0; bb < 16; ++bb) t12[(b0 + bb) * 1024 + kk] = acc[bb];
    }
}

// ---------------------------------------------------------------------------
// Stage 2 (one launch): blocks 0..15 -> w, blocks 16..143 -> beta. No atomics.
//   r[b,k]  = p[b,k]*t1[b,k]
//   w[b,k'] = sum_k W_kb[k'][k]*r[b,k] + t2[b,k']
//   beta[b] = sum_j (b_merge[j]*u[b,j] + b_kb[j]*r[b,j]) + b_attn
// ---------------------------------------------------------------------------
__global__ void k_stage2(const float* __restrict__ p, const float* __restrict__ t12,
                         const float* __restrict__ W_kb, const float* __restrict__ c,
                         const float* __restrict__ W_attn, const float* __restrict__ b_merge,
                         const float* __restrict__ b_kb, const float* __restrict__ b_attn,
                         float* __restrict__ w, float* __restrict__ beta) {
    const int bx = blockIdx.x;
    const int t  = threadIdx.x;

    if (bx < 16) {                        // ---- w ----
        __shared__ float rs[16][64];
        const int kp = (bx & 1) * 256 + t;      // 0..511
        const int b0 = (bx >> 1) * 16;
        float acc[16];
        #pragma unroll
        for (int bb = 0; bb < 16; ++bb) acc[bb] = 0.f;
        for (int k0 = 0; k0 < D; k0 += 64) {
            for (int i = t; i < 16 * 64; i += 256) {
                int bb = i >> 6, kk = i & 63;
                int b = b0 + bb, k = k0 + kk;
                rs[bb][kk] = p[b * D + k] * t12[b * 1024 + k];   // t1 = cols [0,512)
            }
            __syncthreads();
            const float4* wrow = (const float4*)&W_kb[kp * D + k0];
            for (int q = 0; q < 16; ++q) {
                float4 w4 = wrow[q];
                #pragma unroll
                for (int bb = 0; bb < 16; ++bb)
                    acc[bb] += rs[bb][4*q+0] * w4.x + rs[bb][4*q+1] * w4.y
                             + rs[bb][4*q+2] * w4.z + rs[bb][4*q+3] * w4.w;
            }
            __syncthreads();
        }
        #pragma unroll
        for (int bb = 0; bb < 16; ++bb)
            w[(b0 + bb) * D + kp] = acc[bb] + t12[(b0 + bb) * 1024 + 512 + kp];
    } else {                              // ---- beta ----
        const int b = bx - 16;                  // 0..127
        float s = 0.f;
        for (int j = t; j < D; j += 256) {
            float u = c[b * D + j] * W_attn[j];
            float r = p[b * D + j] * t12[b * 1024 + j];
            s += b_merge[j] * u + b_kb[j] * r;
        }
        #pragma unroll
        for (int off = 32; off; off >>= 1) s += __shfl_down(s, off, 64);
        __shared__ float red[4];
        if ((t & 63) == 0) red[t >> 6] = s;
        __syncthreads();
        if (t == 0) beta[b] = red[0] + red[1] + red[2] + red[3] + b_attn[0];
    }
}

// ---------------------------------------------------------------------------
// K_MV: mv_part[b][ks][hw] = sum_{k in chunk ks} KB[b,k,hw]*w[b,k] (+beta once)
// grid 512 (b * 4 k-chunks), block 256. HBM pass over KB (51.4 MB).
// ---------------------------------------------------------------------------
__global__ void k_mv(const float* __restrict__ KB, const float* __restrict__ w,
                     const float* __restrict__ beta, float* __restrict__ mvp) {
    const int b  = blockIdx.x >> 2;
    const int ks = blockIdx.x & 3;
    const int t  = threadIdx.x;
    __shared__ float wl[128];
    if (t < 128) wl[t] = w[b * D + ks * 128 + t];
    __syncthreads();
    if (t < HW) {
        const float* kbp = KB + (size_t)b * D * HW + (size_t)ks * 128 * HW + t;
        float acc = (ks == 0) ? beta[b] : 0.f;
        #pragma unroll 8
        for (int k = 0; k < 128; ++k) acc += kbp[(size_t)k * HW] * wl[k];
        mvp[(b * 4 + ks) * HW + t] = acc;
    }
}

// ---------------------------------------------------------------------------
// K_MNEW: out[b,k] = sum_hw KB[b,k,hw] * mv[b,hw]; mv = sum of 4 partials.
// grid 256 (b * 2 k-halves), block 256. L3-hot second pass over KB.
// ---------------------------------------------------------------------------
__global__ void k_mnew(const float* __restrict__ KB, const float* __restrict__ mvp,
                       float* __restrict__ out) {
    const int b  = blockIdx.x >> 1;
    const int kh = blockIdx.x & 1;
    const int t  = threadIdx.x;
    __shared__ float ml[HW];
    if (t < HW)
        ml[t] = mvp[(b * 4 + 0) * HW + t] + mvp[(b * 4 + 1) * HW + t]
              + mvp[(b * 4 + 2) * HW + t] + mvp[(b * 4 + 3) * HW + t];
    __syncthreads();
    const int k = kh * 256 + t;
    const float4* row = (const float4*)(KB + (size_t)b * D * HW + (size_t)k * HW);
    float acc = 0.f;
    #pragma unroll 7
    for (int h4 = 0; h4 < 49; ++h4) {
        float4 v = row[h4];
        acc += v.x * ml[4*h4+0] + v.y * ml[4*h4+1] + v.z * ml[4*h4+2] + v.w * ml[4*h4+3];
    }
    out[b * D + k] = acc;
}

// ---------------------------------------------------------------------------
extern "C" void kernel_launch(void* const* d_in, const int* in_sizes, int n_in,
                              void* d_out, int out_size, void* d_ws, size_t ws_size,
                              hipStream_t stream) {
    const float* m_prev  = (const float*)d_in[0];
    const float* KB      = (const float*)d_in[1];
    const float* c_i     = (const float*)d_in[2];
    const float* W_m     = (const float*)d_in[3];
    const float* b_m     = (const float*)d_in[4];
    const float* W_kb    = (const float*)d_in[5];
    const float* b_kb    = (const float*)d_in[6];
    const float* W_merge = (const float*)d_in[7];
    const float* b_merge = (const float*)d_in[8];
    const float* W_attn  = (const float*)d_in[9];
    const float* b_attn  = (const float*)d_in[10];
    float* out = (float*)d_out;

    float* ws   = (float*)d_ws;
    float* p    = ws;             // 65536 floats   [128][512]
    float* t12  = ws + 65536;     // 131072 floats  [128][1024]
    float* w    = ws + 196608;    // 65536 floats   [128][512]
    float* beta = ws + 262144;    // 128 floats
    float* mvp  = ws;             // 100352 floats  [128][4][196] — reuses dead p/t12

    k_stage1<<<48, 256, 0, stream>>>(m_prev, W_m, b_m, c_i, W_attn, W_merge, p, t12);
    k_stage2<<<144, 256, 0, stream>>>(p, t12, W_kb, c_i, W_attn, b_merge, b_kb, b_attn, w, beta);
    k_mv    <<<512, 256, 0, stream>>>(KB, w, beta, mvp);
    k_mnew  <<<256, 256, 0, stream>>>(KB, mvp, out);
}

// Round 3
// 50.079 us; speedup vs baseline: 4.3913x; 4.3913x over previous
//
#include <hip/hip_runtime.h>

#define D   512
#define HW  196   // 14*14
#define NS  8     // K-split count for the small GEMMs

// Workspace layout (floats):
//   p_part   [NS][128][512]   @ 0        (524288)
//   t12_part [NS][128][1024]  @ 524288   (1048576)
//   w_part   [NS][128][512]   @ 1572864  (524288)
//   beta     [128]            @ 2097152
//   mvp      [128][4][196]    @ 2097280
// total ~8.8 MB << ws_size (~256 MB per round-1 poison fill)

// ---------------------------------------------------------------------------
// Stage 1 (one launch, 384 blocks): blocks 0..127 -> p partials,
// blocks 128..383 -> t12 partials. Round-1 split-K structure, no atomics.
// ---------------------------------------------------------------------------
__global__ void k_stage1(const float* __restrict__ m_prev, const float* __restrict__ W_m,
                         const float* __restrict__ b_m, const float* __restrict__ c,
                         const float* __restrict__ W_attn, const float* __restrict__ W_merge,
                         float* __restrict__ p_part, float* __restrict__ t12_part) {
    const int bx = blockIdx.x;
    const int t  = threadIdx.x;
    __shared__ float xs[16][64];

    if (bx < 128) {                       // ---- p: grid (jt2, bt8, kt8) ----
        const int jt = bx & 1, bt = (bx >> 1) & 7, kt = bx >> 4;
        const int j  = jt * 256 + t;
        const int b0 = bt * 16;
        const int k0 = kt * 64;
        for (int i = t; i < 16 * 64; i += 256)
            xs[i >> 6][i & 63] = m_prev[(b0 + (i >> 6)) * D + k0 + (i & 63)];
        __syncthreads();
        float acc[16];
        #pragma unroll
        for (int bb = 0; bb < 16; ++bb) acc[bb] = 0.f;
        for (int kk = 0; kk < 64; ++kk) {
            float wv = W_m[(k0 + kk) * D + j];        // coalesced across lanes
            #pragma unroll
            for (int bb = 0; bb < 16; ++bb) acc[bb] += xs[bb][kk] * wv;
        }
        const float bias = (kt == 0) ? b_m[j] : 0.f;  // bias folded into split 0
        #pragma unroll
        for (int bb = 0; bb < 16; ++bb)
            p_part[((size_t)kt * 128 + b0 + bb) * D + j] = acc[bb] + bias;
    } else {                              // ---- t12: grid (kkt4, bt8, jt8) ----
        const int i2 = bx - 128;
        const int kkt = i2 & 3, bt = (i2 >> 2) & 7, jt = i2 >> 5;
        const int kk = kkt * 256 + t;     // 0..1023
        const int b0 = bt * 16;
        const int j0 = jt * 64;
        for (int i = t; i < 16 * 64; i += 256) {
            int bb = i >> 6, jj = i & 63;
            xs[bb][jj] = c[(b0 + bb) * D + j0 + jj] * W_attn[j0 + jj];
        }
        __syncthreads();
        float acc[16];
        #pragma unroll
        for (int bb = 0; bb < 16; ++bb) acc[bb] = 0.f;
        const float4* wrow = (const float4*)&W_merge[(size_t)kk * D + j0];
        for (int q = 0; q < 16; ++q) {
            float4 w4 = wrow[q];
            #pragma unroll
            for (int bb = 0; bb < 16; ++bb)
                acc[bb] += xs[bb][4*q+0] * w4.x + xs[bb][4*q+1] * w4.y
                         + xs[bb][4*q+2] * w4.z + xs[bb][4*q+3] * w4.w;
        }
        #pragma unroll
        for (int bb = 0; bb < 16; ++bb)
            t12_part[((size_t)jt * 128 + b0 + bb) * 1024 + kk] = acc[bb];
    }
}

// ---------------------------------------------------------------------------
// Stage 2 (one launch, 256 blocks): blocks 0..127 -> w partials (folding
// p/t1 partials while staging), blocks 128..255 -> beta. No atomics.
// ---------------------------------------------------------------------------
__global__ void k_stage2(const float* __restrict__ p_part, const float* __restrict__ t12_part,
                         const float* __restrict__ W_kb, const float* __restrict__ c,
                         const float* __restrict__ W_attn, const float* __restrict__ b_merge,
                         const float* __restrict__ b_kb, const float* __restrict__ b_attn,
                         float* __restrict__ w_part, float* __restrict__ beta) {
    const int bx = blockIdx.x;
    const int t  = threadIdx.x;
    __shared__ float rs[16][64];

    if (bx < 128) {                       // ---- w: grid (kpt2, bt8, kt8) ----
        const int kpt = bx & 1, bt = (bx >> 1) & 7, kt = bx >> 4;
        const int kp = kpt * 256 + t;
        const int b0 = bt * 16;
        const int k0 = kt * 64;
        for (int i = t; i < 16 * 64; i += 256) {
            int bb = i >> 6, kk = i & 63;
            int b = b0 + bb, k = k0 + kk;
            float pv = 0.f, tv = 0.f;
            #pragma unroll
            for (int s = 0; s < NS; ++s) {
                pv += p_part[((size_t)s * 128 + b) * D + k];
                tv += t12_part[((size_t)s * 128 + b) * 1024 + k];   // t1 = cols [0,512)
            }
            rs[bb][kk] = pv * tv;
        }
        __syncthreads();
        float acc[16];
        #pragma unroll
        for (int bb = 0; bb < 16; ++bb) acc[bb] = 0.f;
        const float4* wrow = (const float4*)&W_kb[(size_t)kp * D + k0];
        for (int q = 0; q < 16; ++q) {
            float4 w4 = wrow[q];
            #pragma unroll
            for (int bb = 0; bb < 16; ++bb)
                acc[bb] += rs[bb][4*q+0] * w4.x + rs[bb][4*q+1] * w4.y
                         + rs[bb][4*q+2] * w4.z + rs[bb][4*q+3] * w4.w;
        }
        #pragma unroll
        for (int bb = 0; bb < 16; ++bb) {
            float extra = 0.f;
            if (kt == 0) {                // fold t2 into split 0
                #pragma unroll
                for (int s = 0; s < NS; ++s)
                    extra += t12_part[((size_t)s * 128 + b0 + bb) * 1024 + 512 + kp];
            }
            w_part[((size_t)kt * 128 + b0 + bb) * D + kp] = acc[bb] + extra;
        }
    } else {                              // ---- beta ----
        const int b = bx - 128;
        float sum = 0.f;
        for (int j = t; j < D; j += 256) {
            float pv = 0.f, tv = 0.f;
            #pragma unroll
            for (int s = 0; s < NS; ++s) {
                pv += p_part[((size_t)s * 128 + b) * D + j];
                tv += t12_part[((size_t)s * 128 + b) * 1024 + j];
            }
            float u = c[b * D + j] * W_attn[j];
            sum += b_merge[j] * u + b_kb[j] * (pv * tv);
        }
        #pragma unroll
        for (int off = 32; off; off >>= 1) sum += __shfl_down(sum, off, 64);
        __shared__ float red[4];
        if ((t & 63) == 0) red[t >> 6] = sum;
        __syncthreads();
        if (t == 0) beta[b] = red[0] + red[1] + red[2] + red[3] + b_attn[0];
    }
}

// ---------------------------------------------------------------------------
// K_MV: mv_part[b][ks][hw] = sum_{k in chunk ks} KB[b,k,hw]*w[b,k] (+beta once)
// grid 512 (b * 4 k-chunks), block 256. HBM pass over KB (51.4 MB).
// ---------------------------------------------------------------------------
__global__ void k_mv(const float* __restrict__ KB, const float* __restrict__ w_part,
                     const float* __restrict__ beta, float* __restrict__ mvp) {
    const int b  = blockIdx.x >> 2;
    const int ks = blockIdx.x & 3;
    const int t  = threadIdx.x;
    __shared__ float wl[128];
    if (t < 128) {
        float s = 0.f;
        #pragma unroll
        for (int q = 0; q < NS; ++q)
            s += w_part[((size_t)q * 128 + b) * D + ks * 128 + t];
        wl[t] = s;
    }
    __syncthreads();
    if (t < HW) {
        const float* kbp = KB + (size_t)b * D * HW + (size_t)ks * 128 * HW + t;
        float acc = (ks == 0) ? beta[b] : 0.f;
        #pragma unroll 8
        for (int k = 0; k < 128; ++k) acc += kbp[(size_t)k * HW] * wl[k];
        mvp[(b * 4 + ks) * HW + t] = acc;
    }
}

// ---------------------------------------------------------------------------
// K_MNEW: out[b,k] = sum_hw KB[b,k,hw] * mv[b,hw]; mv = sum of 4 partials.
// grid 256 (b * 2 k-halves), block 256. L3-hot second pass over KB.
// ---------------------------------------------------------------------------
__global__ void k_mnew(const float* __restrict__ KB, const float* __restrict__ mvp,
                       float* __restrict__ out) {
    const int b  = blockIdx.x >> 1;
    const int kh = blockIdx.x & 1;
    const int t  = threadIdx.x;
    __shared__ float ml[HW];
    if (t < HW)
        ml[t] = mvp[(b * 4 + 0) * HW + t] + mvp[(b * 4 + 1) * HW + t]
              + mvp[(b * 4 + 2) * HW + t] + mvp[(b * 4 + 3) * HW + t];
    __syncthreads();
    const int k = kh * 256 + t;
    const float4* row = (const float4*)(KB + (size_t)b * D * HW + (size_t)k * HW);
    float acc = 0.f;
    #pragma unroll 7
    for (int h4 = 0; h4 < 49; ++h4) {
        float4 v = row[h4];
        acc += v.x * ml[4*h4+0] + v.y * ml[4*h4+1] + v.z * ml[4*h4+2] + v.w * ml[4*h4+3];
    }
    out[b * D + k] = acc;
}

// ---------------------------------------------------------------------------
extern "C" void kernel_launch(void* const* d_in, const int* in_sizes, int n_in,
                              void* d_out, int out_size, void* d_ws, size_t ws_size,
                              hipStream_t stream) {
    const float* m_prev  = (const float*)d_in[0];
    const float* KB      = (const float*)d_in[1];
    const float* c_i     = (const float*)d_in[2];
    const float* W_m     = (const float*)d_in[3];
    const float* b_m     = (const float*)d_in[4];
    const float* W_kb    = (const float*)d_in[5];
    const float* b_kb    = (const float*)d_in[6];
    const float* W_merge = (const float*)d_in[7];
    const float* b_merge = (const float*)d_in[8];
    const float* W_attn  = (const float*)d_in[9];
    const float* b_attn  = (const float*)d_in[10];
    float* out = (float*)d_out;

    float* ws       = (float*)d_ws;
    float* p_part   = ws;               // 524288
    float* t12_part = ws + 524288;      // 1048576
    float* w_part   = ws + 1572864;     // 524288
    float* beta     = ws + 2097152;     // 128
    float* mvp      = ws + 2097280;     // 100352

    k_stage1<<<384, 256, 0, stream>>>(m_prev, W_m, b_m, c_i, W_attn, W_merge,
                                      p_part, t12_part);
    k_stage2<<<256, 256, 0, stream>>>(p_part, t12_part, W_kb, c_i, W_attn,
                                      b_merge, b_kb, b_attn, w_part, beta);
    k_mv  <<<512, 256, 0, stream>>>(KB, w_part, beta, mvp);
    k_mnew<<<256, 256, 0, stream>>>(KB, mvp, out);
}